// Round 1
// baseline (1001.259 us; speedup 1.0000x reference)
//
#include <hip/hip_runtime.h>
#include <math.h>

#define BB 4
#define VV 256
#define HH 128
#define EPS 1e-5f

__device__ __forceinline__ float sigm_(float x) {
    return 1.0f / (1.0f + __expf(-x));
}

// ---------------------------------------------------------------------------
// K1: six small linears (U1,V1,A1 from h1; U2,V2,A2 from h2)
// grid 128 blocks x 128 threads, 8 rows/block
// ---------------------------------------------------------------------------
struct LinArgs {
    const float* x1; const float* x2;
    const float* W[6]; const float* b[6];
    float* out[6];
};

__global__ __launch_bounds__(128) void k1_linears(LinArgs a) {
    __shared__ float xs[2][8][HH];
    const int t = threadIdx.x;
    const int r0 = blockIdx.x * 8;
    {
        const float4* s1 = (const float4*)(a.x1 + (size_t)r0 * HH);
        const float4* s2 = (const float4*)(a.x2 + (size_t)r0 * HH);
        float4* d1 = (float4*)&xs[0][0][0];
        float4* d2 = (float4*)&xs[1][0][0];
        #pragma unroll
        for (int p = 0; p < 2; ++p) {
            d1[t + p * 128] = s1[t + p * 128];
            d2[t + p * 128] = s2[t + p * 128];
        }
    }
    __syncthreads();
    const int h = t;
    for (int g = 0; g < 6; ++g) {
        const float* W = a.W[g];
        const float (*x)[HH] = (g < 3) ? xs[0] : xs[1];
        float acc[8];
        #pragma unroll
        for (int r = 0; r < 8; ++r) acc[r] = 0.f;
        const float4* Wrow = (const float4*)(W + (size_t)h * HH);
        #pragma unroll 8
        for (int kq = 0; kq < 32; ++kq) {
            float4 w4 = Wrow[kq];
            #pragma unroll
            for (int r = 0; r < 8; ++r) {
                float4 ev = *(const float4*)&x[r][kq * 4];
                acc[r] = fmaf(ev.x, w4.x, acc[r]);
                acc[r] = fmaf(ev.y, w4.y, acc[r]);
                acc[r] = fmaf(ev.z, w4.z, acc[r]);
                acc[r] = fmaf(ev.w, w4.w, acc[r]);
            }
        }
        float bias = a.b[g][h];
        float* O = a.out[g] + (size_t)r0 * HH + h;
        #pragma unroll
        for (int r = 0; r < 8; ++r) O[(size_t)r * HH] = acc[r] + bias;
    }
}

// ---------------------------------------------------------------------------
// K2: per (b,i): e_new = e@W_C^T + b_C + Ah1[b,j]+Ah2[b,i]; store e_new into
// d_out e-region; accumulate h1n_pre row and BN stats (e + h1) atomics.
// grid 1024 blocks x 256 threads. thread: h = t&127, jh = t>>7.
// ---------------------------------------------------------------------------
__global__ __launch_bounds__(256) void k2_main(
    const float* __restrict__ e,
    const float* __restrict__ W_C, const float* __restrict__ b_C,
    const float* __restrict__ A1, const float* __restrict__ A2,
    const float* __restrict__ V1, const float* __restrict__ V2,
    const float* __restrict__ U1,
    float* __restrict__ e_new,
    float* __restrict__ h1p,
    float* __restrict__ stats)
{
    __shared__ float elds[8][HH];
    __shared__ float red[3][HH];
    const int t = threadIdx.x;
    const int h = t & 127;
    const int jh = t >> 7;
    const int bi = blockIdx.x;       // b*V + i
    const int b = bi >> 8;

    // W_C row h in registers (128 VGPRs)
    float4 wv[32];
    const float4* Wrow = (const float4*)(W_C + (size_t)h * HH);
    #pragma unroll
    for (int q = 0; q < 32; ++q) wv[q] = Wrow[q];

    const float bC  = b_C[h];
    const float ah2 = A2[(size_t)bi * HH + h];
    const float vh2 = V2[(size_t)bi * HH + h];
    const float* erow = e + (size_t)bi * (VV * HH);

    float h1acc = 0.f, ssum = 0.f, ssq = 0.f;
    const int rbase = jh * 4;

    for (int j0 = 0; j0 < VV; j0 += 8) {
        __syncthreads();
        ((float4*)&elds[0][0])[t] = ((const float4*)(erow + (size_t)j0 * HH))[t];
        __syncthreads();

        float acc0 = 0.f, acc1 = 0.f, acc2 = 0.f, acc3 = 0.f;
        #pragma unroll
        for (int kq = 0; kq < 32; ++kq) {
            float4 w4 = wv[kq];
            float4 e0 = *(const float4*)&elds[rbase + 0][kq * 4];
            float4 e1 = *(const float4*)&elds[rbase + 1][kq * 4];
            float4 e2 = *(const float4*)&elds[rbase + 2][kq * 4];
            float4 e3 = *(const float4*)&elds[rbase + 3][kq * 4];
            acc0 = fmaf(e0.x, w4.x, acc0); acc0 = fmaf(e0.y, w4.y, acc0);
            acc0 = fmaf(e0.z, w4.z, acc0); acc0 = fmaf(e0.w, w4.w, acc0);
            acc1 = fmaf(e1.x, w4.x, acc1); acc1 = fmaf(e1.y, w4.y, acc1);
            acc1 = fmaf(e1.z, w4.z, acc1); acc1 = fmaf(e1.w, w4.w, acc1);
            acc2 = fmaf(e2.x, w4.x, acc2); acc2 = fmaf(e2.y, w4.y, acc2);
            acc2 = fmaf(e2.z, w4.z, acc2); acc2 = fmaf(e2.w, w4.w, acc2);
            acc3 = fmaf(e3.x, w4.x, acc3); acc3 = fmaf(e3.y, w4.y, acc3);
            acc3 = fmaf(e3.z, w4.z, acc3); acc3 = fmaf(e3.w, w4.w, acc3);
        }
        float accs[4] = {acc0, acc1, acc2, acc3};
        #pragma unroll
        for (int u = 0; u < 4; ++u) {
            int j = j0 + rbase + u;
            int bj = (b << 8) + j;
            float en = accs[u] + bC + A1[(size_t)bj * HH + h] + ah2;
            e_new[((size_t)bi * VV + j) * HH + h] = en;
            float s = sigm_(en);
            h1acc = fmaf(s, V1[(size_t)bj * HH + h] + vh2, h1acc);
            ssum += en;
            ssq = fmaf(en, en, ssq);
        }
    }

    if (jh == 1) { red[0][h] = h1acc; red[1][h] = ssum; red[2][h] = ssq; }
    __syncthreads();
    if (jh == 0) {
        h1acc += red[0][h]; ssum += red[1][h]; ssq += red[2][h];
        float pre = U1[(size_t)bi * HH + h] + h1acc;
        h1p[(size_t)bi * HH + h] = pre;
        atomicAdd(&stats[0 * HH + h], ssum);
        atomicAdd(&stats[1 * HH + h], ssq);
        atomicAdd(&stats[2 * HH + h], pre);
        atomicAdd(&stats[3 * HH + h], pre * pre);
    }
}

// ---------------------------------------------------------------------------
// K4: per (b, J-pair): transposed sweep over I. h2 aggregation + BN(e) +
// relu + residual, e region finalized in place. grid 512 x 256.
// ---------------------------------------------------------------------------
__global__ __launch_bounds__(256) void k4_pass2(
    float* __restrict__ e_io,
    const float* __restrict__ e_in,
    const float* __restrict__ V1, const float* __restrict__ V2,
    const float* __restrict__ U2,
    const float* __restrict__ g_e, const float* __restrict__ be_e,
    float* __restrict__ h2p,
    float* __restrict__ stats)
{
    const int t = threadIdx.x;
    const int h = t & 127;
    const int jsub = t >> 7;
    const int blk = blockIdx.x;       // b*128 + Jpair
    const int b = blk >> 7;
    const int J0 = (blk & 127) << 1;
    const int J = J0 + jsub;
    const int bJ = (b << 8) + J;

    const float inv_n = 1.0f / (float)(BB * VV * VV);
    float mean = stats[0 * HH + h] * inv_n;
    float var  = stats[1 * HH + h] * inv_n - mean * mean;
    float rstd = rsqrtf(var + EPS);
    float sc = rstd * g_e[h];
    float sh = be_e[h] - mean * sc;

    const float vh1 = V1[(size_t)bJ * HH + h];
    float h2acc = 0.f;

    #pragma unroll 8
    for (int I = 0; I < VV; ++I) {
        size_t off = ((size_t)((b * VV + I) * VV) + J0) * HH + t;
        float en = e_io[off];
        float s = sigm_(en);
        h2acc = fmaf(s, vh1 + V2[(size_t)((b << 8) + I) * HH + h], h2acc);
        float bn = fmaf(en, sc, sh);
        e_io[off] = e_in[off] + fmaxf(bn, 0.f);
    }
    float pre = U2[(size_t)bJ * HH + h] + h2acc;
    h2p[(size_t)bJ * HH + h] = pre;
    atomicAdd(&stats[4 * HH + h], pre);
    atomicAdd(&stats[5 * HH + h], pre * pre);
}

// ---------------------------------------------------------------------------
// K5: finalize h1_out, h2_out = x_in + relu(bn(pre)). grid 128 x 256, 8/thread.
// ---------------------------------------------------------------------------
__global__ __launch_bounds__(256) void k5_final(
    const float* __restrict__ h1_in, const float* __restrict__ h2_in,
    const float* __restrict__ h1p, const float* __restrict__ h2p,
    const float* __restrict__ g1, const float* __restrict__ be1,
    const float* __restrict__ g2, const float* __restrict__ be2,
    float* __restrict__ out,
    const float* __restrict__ stats)
{
    const float inv_n = 1.0f / 1024.0f;
    int idx0 = blockIdx.x * 2048 + threadIdx.x;
    #pragma unroll
    for (int p = 0; p < 8; ++p) {
        int idx = idx0 + p * 256;
        int region = idx >> 17;           // 0: h1, 1: h2
        int local = idx & 131071;
        int h = idx & 127;
        float ssum = stats[(2 + 2 * region) * HH + h];
        float ssq  = stats[(3 + 2 * region) * HH + h];
        float mean = ssum * inv_n;
        float var  = ssq * inv_n - mean * mean;
        float rstd = rsqrtf(var + EPS);
        const float* g  = region ? g2 : g1;
        const float* be = region ? be2 : be1;
        float sc = rstd * g[h];
        float sh = be[h] - mean * sc;
        const float* xin = region ? h2_in : h1_in;
        const float* pre = region ? h2p : h1p;
        out[idx] = xin[local] + fmaxf(fmaf(pre[local], sc, sh), 0.f);
    }
}

// ---------------------------------------------------------------------------
extern "C" void kernel_launch(void* const* d_in, const int* in_sizes, int n_in,
                              void* d_out, int out_size, void* d_ws, size_t ws_size,
                              hipStream_t stream) {
    const float* h1   = (const float*)d_in[0];
    const float* h2   = (const float*)d_in[1];
    const float* e    = (const float*)d_in[2];
    // d_in[3] = graph (unused for sum aggregation)
    const float* W_U1 = (const float*)d_in[4];
    const float* b_U1 = (const float*)d_in[5];
    const float* W_U2 = (const float*)d_in[6];
    const float* b_U2 = (const float*)d_in[7];
    const float* W_V1 = (const float*)d_in[8];
    const float* b_V1 = (const float*)d_in[9];
    const float* W_V2 = (const float*)d_in[10];
    const float* b_V2 = (const float*)d_in[11];
    const float* W_A1 = (const float*)d_in[12];
    const float* b_A1 = (const float*)d_in[13];
    const float* W_A2 = (const float*)d_in[14];
    const float* b_A2 = (const float*)d_in[15];
    const float* W_C  = (const float*)d_in[16];
    const float* b_C  = (const float*)d_in[17];
    const float* g_h1 = (const float*)d_in[18];
    const float* be_h1= (const float*)d_in[19];
    const float* g_h2 = (const float*)d_in[20];
    const float* be_h2= (const float*)d_in[21];
    const float* g_e  = (const float*)d_in[22];
    const float* be_e = (const float*)d_in[23];

    float* ws = (float*)d_ws;
    const int S = BB * VV * HH;  // 131072
    float* U1 = ws + 0 * (size_t)S;
    float* U2 = ws + 1 * (size_t)S;
    float* V1 = ws + 2 * (size_t)S;
    float* V2 = ws + 3 * (size_t)S;
    float* A1 = ws + 4 * (size_t)S;
    float* A2 = ws + 5 * (size_t)S;
    float* h1p = ws + 6 * (size_t)S;
    float* h2p = ws + 7 * (size_t)S;
    float* stats = ws + 8 * (size_t)S;  // 6*128 floats

    float* out = (float*)d_out;
    float* eo = out + 2 * (size_t)S;    // e region doubles as e_new scratch

    hipMemsetAsync(stats, 0, 6 * HH * sizeof(float), stream);

    LinArgs la;
    la.x1 = h1; la.x2 = h2;
    la.W[0] = W_U1; la.b[0] = b_U1; la.out[0] = U1;
    la.W[1] = W_V1; la.b[1] = b_V1; la.out[1] = V1;
    la.W[2] = W_A1; la.b[2] = b_A1; la.out[2] = A1;
    la.W[3] = W_U2; la.b[3] = b_U2; la.out[3] = U2;
    la.W[4] = W_V2; la.b[4] = b_V2; la.out[4] = V2;
    la.W[5] = W_A2; la.b[5] = b_A2; la.out[5] = A2;
    k1_linears<<<128, 128, 0, stream>>>(la);

    k2_main<<<BB * VV, 256, 0, stream>>>(e, W_C, b_C, A1, A2, V1, V2, U1,
                                         eo, h1p, stats);

    k4_pass2<<<BB * VV / 2, 256, 0, stream>>>(eo, e, V1, V2, U2, g_e, be_e,
                                              h2p, stats);

    k5_final<<<128, 256, 0, stream>>>(h1, h2, h1p, h2p,
                                      g_h1, be_h1, g_h2, be_h2, out, stats);
}

// Round 2
// 221.399 us; speedup vs baseline: 4.5224x; 4.5224x over previous
//
#include <hip/hip_runtime.h>
#include <math.h>

#define BB 4
#define VV 256
#define HH 128
#define EPS 1e-5f

typedef __attribute__((ext_vector_type(8))) short short8;
typedef __attribute__((ext_vector_type(8))) __bf16 bf16x8;
typedef __attribute__((ext_vector_type(4))) float f32x4;

__device__ __forceinline__ float sigm_(float x) {
    return 1.0f / (1.0f + __expf(-x));
}

__device__ __forceinline__ bf16x8 as_bf(short8 s) {
    union { short8 s; bf16x8 b; } u; u.s = s; return u.b;
}

// split x into hi (bf16 RNE) + lo (bf16 trunc of residual)
__device__ __forceinline__ void split8(const float4 x0, const float4 x1,
                                       short8& hi, short8& lo) {
    float xs[8] = {x0.x, x0.y, x0.z, x0.w, x1.x, x1.y, x1.z, x1.w};
    #pragma unroll
    for (int i = 0; i < 8; ++i) {
        unsigned u = __float_as_uint(xs[i]);
        unsigned hr = (u + 0x7fffu + ((u >> 16) & 1u)) & 0xffff0000u;
        hi[i] = (short)(hr >> 16);
        float r = xs[i] - __uint_as_float(hr);
        lo[i] = (short)(__float_as_uint(r) >> 16);
    }
}

// ---------------------------------------------------------------------------
// K0: split W_C into fragment-major bf16 hi/lo planes.
// layout: short8 index ((kstep*8+nsub)*2 + s)*64 + lane ; per-lane 8 k-elems
// n = nsub*16 + (lane&15), k = kstep*32 + (lane>>4)*8 + i
// ---------------------------------------------------------------------------
__global__ __launch_bounds__(256) void k0_splitW(const float* __restrict__ W_C,
                                                 short* __restrict__ Whl) {
    int t = blockIdx.x * 256 + threadIdx.x;   // 0..2047
    int lane = t & 63;
    int grp = t >> 6;                         // kstep*8 + nsub
    int kstep = grp >> 3, nsub = grp & 7;
    int n = nsub * 16 + (lane & 15);
    int kb = kstep * 32 + ((lane >> 4) & 3) * 8;
    const float4* src = (const float4*)(W_C + (size_t)n * HH + kb);
    float4 x0 = src[0], x1 = src[1];
    short8 hi, lo;
    split8(x0, x1, hi, lo);
    short8* dst = (short8*)Whl;
    dst[(grp * 2 + 0) * 64 + lane] = hi;
    dst[(grp * 2 + 1) * 64 + lane] = lo;
}

// ---------------------------------------------------------------------------
// K1: six small linears (U1,V1,A1 from h1; U2,V2,A2 from h2)
// ---------------------------------------------------------------------------
struct LinArgs {
    const float* x1; const float* x2;
    const float* W[6]; const float* b[6];
    float* out[6];
};

__global__ __launch_bounds__(128) void k1_linears(LinArgs a) {
    __shared__ float xs[2][8][HH];
    const int t = threadIdx.x;
    const int r0 = blockIdx.x * 8;
    {
        const float4* s1 = (const float4*)(a.x1 + (size_t)r0 * HH);
        const float4* s2 = (const float4*)(a.x2 + (size_t)r0 * HH);
        float4* d1 = (float4*)&xs[0][0][0];
        float4* d2 = (float4*)&xs[1][0][0];
        #pragma unroll
        for (int p = 0; p < 2; ++p) {
            d1[t + p * 128] = s1[t + p * 128];
            d2[t + p * 128] = s2[t + p * 128];
        }
    }
    __syncthreads();
    const int h = t;
    for (int g = 0; g < 6; ++g) {
        const float* W = a.W[g];
        const float (*x)[HH] = (g < 3) ? xs[0] : xs[1];
        float acc[8];
        #pragma unroll
        for (int r = 0; r < 8; ++r) acc[r] = 0.f;
        const float4* Wrow = (const float4*)(W + (size_t)h * HH);
        #pragma unroll 8
        for (int kq = 0; kq < 32; ++kq) {
            float4 w4 = Wrow[kq];
            #pragma unroll
            for (int r = 0; r < 8; ++r) {
                float4 ev = *(const float4*)&x[r][kq * 4];
                acc[r] = fmaf(ev.x, w4.x, acc[r]);
                acc[r] = fmaf(ev.y, w4.y, acc[r]);
                acc[r] = fmaf(ev.z, w4.z, acc[r]);
                acc[r] = fmaf(ev.w, w4.w, acc[r]);
            }
        }
        float bias = a.b[g][h];
        float* O = a.out[g] + (size_t)r0 * HH + h;
        #pragma unroll
        for (int r = 0; r < 8; ++r) O[(size_t)r * HH] = acc[r] + bias;
    }
}

// ---------------------------------------------------------------------------
// K2 (MFMA): per (b,i): e_new = e@W_C^T + bC + A1[j] + A2[i]; h1 aggregation,
// BN stats. 512 threads = 8 waves; wave w owns j in [w*32, w*32+32).
// 16x16x32 bf16 MFMA, split hi/lo (3 products). No LDS in main loop.
// ---------------------------------------------------------------------------
__global__ __launch_bounds__(512) void k2_main(
    const float* __restrict__ e,
    const short* __restrict__ Whl,
    const float* __restrict__ b_C,
    const float* __restrict__ A1, const float* __restrict__ A2,
    const float* __restrict__ V1, const float* __restrict__ V2,
    const float* __restrict__ U1,
    float* __restrict__ e_new,
    float* __restrict__ h1p,
    float* __restrict__ stats)
{
    __shared__ float red[8][3][8][16];   // [wave][qty][nsub][lane15]
    const int t = threadIdx.x;
    const int l = t & 63;
    const int w = t >> 6;
    const int l15 = l & 15;
    const int lq = (l >> 4) & 3;
    const int bi = blockIdx.x;           // b*V + i
    const int b = bi >> 8;

    const float* ebase = e + (size_t)bi * (VV * HH);
    const short8* Wf = (const short8*)Whl;

    f32x4 acc[2][8];
    #pragma unroll
    for (int js = 0; js < 2; ++js)
        #pragma unroll
        for (int ns = 0; ns < 8; ++ns)
            acc[js][ns] = (f32x4){0.f, 0.f, 0.f, 0.f};

    for (int kstep = 0; kstep < 4; ++kstep) {
        // B fragments (L1-resident after first block touches them)
        short8 bh[8], bl[8];
        #pragma unroll
        for (int ns = 0; ns < 8; ++ns) {
            int grp = kstep * 8 + ns;
            bh[ns] = Wf[(grp * 2 + 0) * 64 + l];
            bl[ns] = Wf[(grp * 2 + 1) * 64 + l];
        }
        // A fragments: e rows, fp32 -> hi/lo bf16
        short8 ah[2], al[2];
        #pragma unroll
        for (int js = 0; js < 2; ++js) {
            int row = w * 32 + js * 16 + l15;
            const float4* p = (const float4*)(ebase + (size_t)row * HH +
                                              kstep * 32 + lq * 8);
            float4 x0 = p[0], x1 = p[1];
            split8(x0, x1, ah[js], al[js]);
        }
        #pragma unroll
        for (int ns = 0; ns < 8; ++ns) {
            #pragma unroll
            for (int js = 0; js < 2; ++js) {
                acc[js][ns] = __builtin_amdgcn_mfma_f32_16x16x32_bf16(
                    as_bf(ah[js]), as_bf(bh[ns]), acc[js][ns], 0, 0, 0);
                acc[js][ns] = __builtin_amdgcn_mfma_f32_16x16x32_bf16(
                    as_bf(ah[js]), as_bf(bl[ns]), acc[js][ns], 0, 0, 0);
                acc[js][ns] = __builtin_amdgcn_mfma_f32_16x16x32_bf16(
                    as_bf(al[js]), as_bf(bh[ns]), acc[js][ns], 0, 0, 0);
            }
        }
    }

    // ---- epilogue: bias + A1 + A2, store e_new, sigmoid, h1 agg, BN stats
    float bCv[8], ah2v[8], vh2v[8];
    #pragma unroll
    for (int ns = 0; ns < 8; ++ns) {
        int n = ns * 16 + l15;
        bCv[ns]  = b_C[n];
        ah2v[ns] = A2[(size_t)bi * HH + n];
        vh2v[ns] = V2[(size_t)bi * HH + n];
    }
    float h1a[8], es[8], eq[8];
    #pragma unroll
    for (int ns = 0; ns < 8; ++ns) { h1a[ns] = 0.f; es[ns] = 0.f; eq[ns] = 0.f; }

    #pragma unroll
    for (int js = 0; js < 2; ++js) {
        #pragma unroll
        for (int r = 0; r < 4; ++r) {
            int j = w * 32 + js * 16 + lq * 4 + r;
            size_t base = (size_t)(b * VV + j) * HH;
            size_t obase = ((size_t)bi * VV + j) * HH;
            #pragma unroll
            for (int ns = 0; ns < 8; ++ns) {
                int n = ns * 16 + l15;
                float en = acc[js][ns][r] + bCv[ns] + A1[base + n] + ah2v[ns];
                e_new[obase + n] = en;
                float s = sigm_(en);
                h1a[ns] = fmaf(s, V1[base + n] + vh2v[ns], h1a[ns]);
                es[ns] += en;
                eq[ns] = fmaf(en, en, eq[ns]);
            }
        }
    }

    // reduce across the 4 lane-groups (same channel, different j)
    #pragma unroll
    for (int ns = 0; ns < 8; ++ns) {
        h1a[ns] += __shfl_xor(h1a[ns], 16);
        h1a[ns] += __shfl_xor(h1a[ns], 32);
        es[ns]  += __shfl_xor(es[ns], 16);
        es[ns]  += __shfl_xor(es[ns], 32);
        eq[ns]  += __shfl_xor(eq[ns], 16);
        eq[ns]  += __shfl_xor(eq[ns], 32);
    }
    if (l < 16) {
        #pragma unroll
        for (int ns = 0; ns < 8; ++ns) {
            red[w][0][ns][l15] = h1a[ns];
            red[w][1][ns][l15] = es[ns];
            red[w][2][ns][l15] = eq[ns];
        }
    }
    __syncthreads();
    if (t < 128) {
        int ns = t >> 4, li = t & 15;
        float h1t = 0.f, est = 0.f, eqt = 0.f;
        #pragma unroll
        for (int ww = 0; ww < 8; ++ww) {
            h1t += red[ww][0][ns][li];
            est += red[ww][1][ns][li];
            eqt += red[ww][2][ns][li];
        }
        int n = t;
        float pre = U1[(size_t)bi * HH + n] + h1t;
        h1p[(size_t)bi * HH + n] = pre;
        atomicAdd(&stats[0 * HH + n], est);
        atomicAdd(&stats[1 * HH + n], eqt);
        atomicAdd(&stats[2 * HH + n], pre);
        atomicAdd(&stats[3 * HH + n], pre * pre);
    }
}

// ---------------------------------------------------------------------------
// K4: per (b, J-pair): transposed sweep over I. h2 aggregation + BN(e) +
// relu + residual, e region finalized in place. grid 512 x 256.
// ---------------------------------------------------------------------------
__global__ __launch_bounds__(256) void k4_pass2(
    float* __restrict__ e_io,
    const float* __restrict__ e_in,
    const float* __restrict__ V1, const float* __restrict__ V2,
    const float* __restrict__ U2,
    const float* __restrict__ g_e, const float* __restrict__ be_e,
    float* __restrict__ h2p,
    float* __restrict__ stats)
{
    const int t = threadIdx.x;
    const int h = t & 127;
    const int jsub = t >> 7;
    const int blk = blockIdx.x;       // b*128 + Jpair
    const int b = blk >> 7;
    const int J0 = (blk & 127) << 1;
    const int J = J0 + jsub;
    const int bJ = (b << 8) + J;

    const float inv_n = 1.0f / (float)(BB * VV * VV);
    float mean = stats[0 * HH + h] * inv_n;
    float var  = stats[1 * HH + h] * inv_n - mean * mean;
    float rstd = rsqrtf(var + EPS);
    float sc = rstd * g_e[h];
    float sh = be_e[h] - mean * sc;

    const float vh1 = V1[(size_t)bJ * HH + h];
    float h2acc = 0.f;

    #pragma unroll 8
    for (int I = 0; I < VV; ++I) {
        size_t off = ((size_t)((b * VV + I) * VV) + J0) * HH + t;
        float en = e_io[off];
        float s = sigm_(en);
        h2acc = fmaf(s, vh1 + V2[(size_t)((b << 8) + I) * HH + h], h2acc);
        float bn = fmaf(en, sc, sh);
        e_io[off] = e_in[off] + fmaxf(bn, 0.f);
    }
    float pre = U2[(size_t)bJ * HH + h] + h2acc;
    h2p[(size_t)bJ * HH + h] = pre;
    atomicAdd(&stats[4 * HH + h], pre);
    atomicAdd(&stats[5 * HH + h], pre * pre);
}

// ---------------------------------------------------------------------------
// K5: finalize h1_out, h2_out = x_in + relu(bn(pre)).
// ---------------------------------------------------------------------------
__global__ __launch_bounds__(256) void k5_final(
    const float* __restrict__ h1_in, const float* __restrict__ h2_in,
    const float* __restrict__ h1p, const float* __restrict__ h2p,
    const float* __restrict__ g1, const float* __restrict__ be1,
    const float* __restrict__ g2, const float* __restrict__ be2,
    float* __restrict__ out,
    const float* __restrict__ stats)
{
    const float inv_n = 1.0f / 1024.0f;
    int idx0 = blockIdx.x * 2048 + threadIdx.x;
    #pragma unroll
    for (int p = 0; p < 8; ++p) {
        int idx = idx0 + p * 256;
        int region = idx >> 17;           // 0: h1, 1: h2
        int local = idx & 131071;
        int h = idx & 127;
        float ssum = stats[(2 + 2 * region) * HH + h];
        float ssq  = stats[(3 + 2 * region) * HH + h];
        float mean = ssum * inv_n;
        float var  = ssq * inv_n - mean * mean;
        float rstd = rsqrtf(var + EPS);
        const float* g  = region ? g2 : g1;
        const float* be = region ? be2 : be1;
        float sc = rstd * g[h];
        float sh = be[h] - mean * sc;
        const float* xin = region ? h2_in : h1_in;
        const float* pre = region ? h2p : h1p;
        out[idx] = xin[local] + fmaxf(fmaf(pre[local], sc, sh), 0.f);
    }
}

// ---------------------------------------------------------------------------
extern "C" void kernel_launch(void* const* d_in, const int* in_sizes, int n_in,
                              void* d_out, int out_size, void* d_ws, size_t ws_size,
                              hipStream_t stream) {
    const float* h1   = (const float*)d_in[0];
    const float* h2   = (const float*)d_in[1];
    const float* e    = (const float*)d_in[2];
    // d_in[3] = graph (unused for sum aggregation)
    const float* W_U1 = (const float*)d_in[4];
    const float* b_U1 = (const float*)d_in[5];
    const float* W_U2 = (const float*)d_in[6];
    const float* b_U2 = (const float*)d_in[7];
    const float* W_V1 = (const float*)d_in[8];
    const float* b_V1 = (const float*)d_in[9];
    const float* W_V2 = (const float*)d_in[10];
    const float* b_V2 = (const float*)d_in[11];
    const float* W_A1 = (const float*)d_in[12];
    const float* b_A1 = (const float*)d_in[13];
    const float* W_A2 = (const float*)d_in[14];
    const float* b_A2 = (const float*)d_in[15];
    const float* W_C  = (const float*)d_in[16];
    const float* b_C  = (const float*)d_in[17];
    const float* g_h1 = (const float*)d_in[18];
    const float* be_h1= (const float*)d_in[19];
    const float* g_h2 = (const float*)d_in[20];
    const float* be_h2= (const float*)d_in[21];
    const float* g_e  = (const float*)d_in[22];
    const float* be_e = (const float*)d_in[23];

    float* ws = (float*)d_ws;
    const int S = BB * VV * HH;  // 131072
    float* U1 = ws + 0 * (size_t)S;
    float* U2 = ws + 1 * (size_t)S;
    float* V1 = ws + 2 * (size_t)S;
    float* V2 = ws + 3 * (size_t)S;
    float* A1 = ws + 4 * (size_t)S;
    float* A2 = ws + 5 * (size_t)S;
    float* h1p = ws + 6 * (size_t)S;
    float* h2p = ws + 7 * (size_t)S;
    float* stats = ws + 8 * (size_t)S;       // 6*128 floats
    short* Whl  = (short*)(stats + 768);     // 2*128*128 bf16 = 64 KB

    float* out = (float*)d_out;
    float* eo = out + 2 * (size_t)S;    // e region doubles as e_new scratch

    hipMemsetAsync(stats, 0, 6 * HH * sizeof(float), stream);

    k0_splitW<<<8, 256, 0, stream>>>(W_C, Whl);

    LinArgs la;
    la.x1 = h1; la.x2 = h2;
    la.W[0] = W_U1; la.b[0] = b_U1; la.out[0] = U1;
    la.W[1] = W_V1; la.b[1] = b_V1; la.out[1] = V1;
    la.W[2] = W_A1; la.b[2] = b_A1; la.out[2] = A1;
    la.W[3] = W_U2; la.b[3] = b_U2; la.out[3] = U2;
    la.W[4] = W_V2; la.b[4] = b_V2; la.out[4] = V2;
    la.W[5] = W_A2; la.b[5] = b_A2; la.out[5] = A2;
    k1_linears<<<128, 128, 0, stream>>>(la);

    k2_main<<<BB * VV, 512, 0, stream>>>(e, Whl, b_C, A1, A2, V1, V2, U1,
                                         eo, h1p, stats);

    k4_pass2<<<BB * VV / 2, 256, 0, stream>>>(eo, e, V1, V2, U2, g_e, be_e,
                                              h2p, stats);

    k5_final<<<128, 256, 0, stream>>>(h1, h2, h1p, h2p,
                                      g_h1, be_h1, g_h2, be_h2, out, stats);
}